// Round 1
// baseline (464.833 us; speedup 1.0000x reference)
//
#include <hip/hip_runtime.h>

#define TT 16384
#define DD 4096
#define OO 4096
#define NE 8
#define RRK 64

typedef _Float16 f16x8 __attribute__((ext_vector_type(8)));
typedef float f32x4 __attribute__((ext_vector_type(4)));

// workspace layout (bytes)
#define CNT_OFF 0            // 8 ints: per-adapter cursors/counts
#define PERM_OFF 1024        // 8*TT ints = 512KB: token ids bucketed by adapter
#define H_OFF (1u << 20)     // TT*64 f16 = 2MB: intermediate H (scale folded in)
#define AT_OFF (3u << 20)    // 8*64*4096 f16 = 4MB: A transposed [e][r][k]
#define BT_OFF (7u << 20)    // 8*4096*64 f16 = 4MB: B transposed [e][o][r]

// ---------------------------------------------------------------------------
// prep: scatter tokens into per-adapter buckets; transpose+cast A and B to f16
// ---------------------------------------------------------------------------
__global__ void prep_kernel(const int* __restrict__ ids,
                            const float* __restrict__ A,
                            const float* __restrict__ B,
                            int* __restrict__ cnt,
                            int* __restrict__ perm,
                            _Float16* __restrict__ At,
                            _Float16* __restrict__ Bt) {
  const int bid = blockIdx.x, tid = threadIdx.x;
  if (bid < 64) {                      // scatter: 64 blocks * 256 = 16384 tokens
    int t = bid * 256 + tid;
    int e = ids[t];
    int pos = atomicAdd(&cnt[e], 1);
    perm[e * TT + pos] = t;
    return;
  }
  __shared__ float tile[64][65];
  if (bid < 576) {                     // A[e][k][r] -> At[e][r][k]
    int idx = bid - 64;
    int e = idx >> 6, kb = (idx & 63) << 6;
    #pragma unroll
    for (int i = 0; i < 16; ++i) {
      int lin = i * 256 + tid;
      int kr = lin >> 6, r = lin & 63;
      tile[kr][r] = A[((size_t)e * DD + kb + kr) * RRK + r];
    }
    __syncthreads();
    #pragma unroll
    for (int i = 0; i < 16; ++i) {
      int lin = i * 256 + tid;
      int r = lin >> 6, kk = lin & 63;
      At[((size_t)e * RRK + r) * DD + kb + kk] = (_Float16)tile[kk][r];
    }
  } else {                             // B[e][r][o] -> Bt[e][o][r]
    int idx = bid - 576;
    int e = idx >> 6, ob = (idx & 63) << 6;
    #pragma unroll
    for (int i = 0; i < 16; ++i) {
      int lin = i * 256 + tid;
      int r = lin >> 6, o = lin & 63;
      tile[r][o] = B[((size_t)e * RRK + r) * OO + ob + o];
    }
    __syncthreads();
    #pragma unroll
    for (int i = 0; i < 16; ++i) {
      int lin = i * 256 + tid;
      int o = lin >> 6, r2 = lin & 63;
      Bt[((size_t)e * OO + ob + o) * RRK + r2] = (_Float16)tile[r2][o];
    }
  }
}

// ---------------------------------------------------------------------------
// stage 1: H[t][:] = (x[t] @ A[e]) * s_e   grouped by adapter, f16 MFMA
// tile: 64 tokens x 64 (full R), K=4096 loop in steps of 64. 4 waves.
// ---------------------------------------------------------------------------
__global__ __launch_bounds__(256, 2)
void lora_stage1(const float* __restrict__ x,
                 const _Float16* __restrict__ At,
                 const float* __restrict__ scaling,
                 const int* __restrict__ cnt,
                 const int* __restrict__ perm,
                 _Float16* __restrict__ H) {
  __shared__ _Float16 Xs[64][72];   // padded pitch: 144B -> 2-way banks only
  __shared__ _Float16 As[64][72];
  __shared__ int toks[64];
  const int tid = threadIdx.x;
  const int lane = tid & 63, w = tid >> 6;

  int tot = 0;
  #pragma unroll
  for (int ee = 0; ee < NE; ++ee) tot += (cnt[ee] + 63) >> 6;

  for (int wi = blockIdx.x; wi < tot; wi += gridDim.x) {
    int e = 0, base = 0, n_e = 0;
    {
      int acc0 = 0;
      #pragma unroll
      for (int ee = 0; ee < NE; ++ee) {
        int c = cnt[ee];
        int tl = (c + 63) >> 6;
        if (wi >= acc0 && wi < acc0 + tl) { e = ee; base = acc0; n_e = c; }
        acc0 += tl;
      }
    }
    int m0 = (wi - base) << 6;

    if (tid < 64) {
      int rloc = m0 + tid;
      toks[tid] = (rloc < n_e) ? perm[e * TT + rloc] : -1;
    }
    __syncthreads();

    const int srow = tid >> 2;           // 0..63: token row (Xs) / r row (As)
    const int seg = (tid & 3) << 4;      // 0,16,32,48: k segment
    int tk0 = toks[srow];
    if (tk0 < 0) tk0 = toks[0];          // row 0 of an existing tile is valid
    const float* xp = x + (size_t)tk0 * DD + seg;
    const _Float16* ap = At + ((size_t)e * RRK + srow) * DD + seg;

    f32x4 acc[4] = {};

    for (int k0 = 0; k0 < DD; k0 += 64) {
      float4 v0 = *(const float4*)(xp + k0);
      float4 v1 = *(const float4*)(xp + k0 + 4);
      float4 v2 = *(const float4*)(xp + k0 + 8);
      float4 v3 = *(const float4*)(xp + k0 + 12);
      f16x8 xa, xb;
      xa[0] = (_Float16)v0.x; xa[1] = (_Float16)v0.y;
      xa[2] = (_Float16)v0.z; xa[3] = (_Float16)v0.w;
      xa[4] = (_Float16)v1.x; xa[5] = (_Float16)v1.y;
      xa[6] = (_Float16)v1.z; xa[7] = (_Float16)v1.w;
      xb[0] = (_Float16)v2.x; xb[1] = (_Float16)v2.y;
      xb[2] = (_Float16)v2.z; xb[3] = (_Float16)v2.w;
      xb[4] = (_Float16)v3.x; xb[5] = (_Float16)v3.y;
      xb[6] = (_Float16)v3.z; xb[7] = (_Float16)v3.w;
      *(f16x8*)&Xs[srow][seg] = xa;
      *(f16x8*)&Xs[srow][seg + 8] = xb;
      *(f16x8*)&As[srow][seg] = *(const f16x8*)(ap + k0);
      *(f16x8*)&As[srow][seg + 8] = *(const f16x8*)(ap + k0 + 8);
      __syncthreads();

      const int mr = w * 16 + (lane & 15);
      const int kq = (lane >> 4) << 3;
      #pragma unroll
      for (int ks = 0; ks < 2; ++ks) {
        f16x8 af = *(const f16x8*)&Xs[mr][ks * 32 + kq];
        #pragma unroll
        for (int nf = 0; nf < 4; ++nf) {
          f16x8 bfr = *(const f16x8*)&As[nf * 16 + (lane & 15)][ks * 32 + kq];
          acc[nf] = __builtin_amdgcn_mfma_f32_16x16x32_f16(af, bfr, acc[nf], 0, 0, 0);
        }
      }
      __syncthreads();
    }

    // epilogue: D layout col=lane&15, row=(lane>>4)*4+reg; fold scaling here
    float s = scaling[e];
    const int rq = (lane >> 4) << 2;
    #pragma unroll
    for (int rg = 0; rg < 4; ++rg) {
      int tk = toks[w * 16 + rq + rg];
      if (tk >= 0) {
        #pragma unroll
        for (int nf = 0; nf < 4; ++nf) {
          H[(size_t)tk * RRK + nf * 16 + (lane & 15)] = (_Float16)(acc[nf][rg] * s);
        }
      }
    }
    __syncthreads();
  }
}

// ---------------------------------------------------------------------------
// stage 2: out[t][:] = base[t][:] + H[t] @ B[e]   tile 64 tokens x 256 cols
// K=64 (single stage). grid-stride over runtime tile count.
// ---------------------------------------------------------------------------
__global__ __launch_bounds__(256, 2)
void lora_stage2(const float* __restrict__ baseo,
                 const _Float16* __restrict__ Bt,
                 const _Float16* __restrict__ H,
                 const int* __restrict__ cnt,
                 const int* __restrict__ perm,
                 float* __restrict__ out) {
  __shared__ _Float16 Hs[64][72];
  __shared__ _Float16 Bs[256][72];
  __shared__ int toks[64];
  const int tid = threadIdx.x;
  const int lane = tid & 63, w = tid >> 6;

  int tot = 0;
  #pragma unroll
  for (int ee = 0; ee < NE; ++ee) tot += ((cnt[ee] + 63) >> 6) << 4;

  for (int wi = blockIdx.x; wi < tot; wi += gridDim.x) {
    int e = 0, base = 0, n_e = 0;
    {
      int acc0 = 0;
      #pragma unroll
      for (int ee = 0; ee < NE; ++ee) {
        int c = cnt[ee];
        int tl = ((c + 63) >> 6) << 4;
        if (wi >= acc0 && wi < acc0 + tl) { e = ee; base = acc0; n_e = c; }
        acc0 += tl;
      }
    }
    int local = wi - base;
    int tiles_m = (n_e + 63) >> 6;
    int mt = local % tiles_m;           // consecutive blocks share the B tile
    int nt = local / tiles_m;
    int m0 = mt << 6, o0 = nt << 8;

    if (tid < 64) {
      int rloc = m0 + tid;
      toks[tid] = (rloc < n_e) ? perm[e * TT + rloc] : -1;
    }
    __syncthreads();

    // stage Bs: 256 cols x 64 k
    {
      const f16x8* bp = (const f16x8*)(Bt + ((size_t)e * OO + o0 + tid) * RRK);
      #pragma unroll
      for (int j = 0; j < 8; ++j) *(f16x8*)&Bs[tid][j * 8] = bp[j];
    }
    // stage Hs: 64 token rows x 64 r
    {
      int srow = tid >> 2, seg = (tid & 3) << 4;
      int tk = toks[srow];
      if (tk < 0) tk = toks[0];
      const f16x8* hp = (const f16x8*)(H + (size_t)tk * RRK + seg);
      *(f16x8*)&Hs[srow][seg] = hp[0];
      *(f16x8*)&Hs[srow][seg + 8] = hp[1];
    }
    __syncthreads();

    f32x4 acc[16] = {};
    const int mr = w * 16 + (lane & 15);
    const int kq = (lane >> 4) << 3;
    #pragma unroll
    for (int ks = 0; ks < 2; ++ks) {
      f16x8 af = *(const f16x8*)&Hs[mr][ks * 32 + kq];
      #pragma unroll
      for (int nf = 0; nf < 16; ++nf) {
        f16x8 bfr = *(const f16x8*)&Bs[nf * 16 + (lane & 15)][ks * 32 + kq];
        acc[nf] = __builtin_amdgcn_mfma_f32_16x16x32_f16(af, bfr, acc[nf], 0, 0, 0);
      }
    }

    const int rq = (lane >> 4) << 2;
    int tks[4];
    #pragma unroll
    for (int rg = 0; rg < 4; ++rg) tks[rg] = toks[w * 16 + rq + rg];
    #pragma unroll
    for (int nf = 0; nf < 16; ++nf) {
      int col = o0 + nf * 16 + (lane & 15);
      #pragma unroll
      for (int rg = 0; rg < 4; ++rg) {
        if (tks[rg] >= 0) {
          size_t off = (size_t)tks[rg] * OO + col;
          out[off] = baseo[off] + acc[nf][rg];
        }
      }
    }
    __syncthreads();
  }
}

extern "C" void kernel_launch(void* const* d_in, const int* in_sizes, int n_in,
                              void* d_out, int out_size, void* d_ws, size_t ws_size,
                              hipStream_t stream) {
  const float* x = (const float*)d_in[0];
  const float* baseo = (const float*)d_in[1];
  const float* A = (const float*)d_in[2];
  const float* B = (const float*)d_in[3];
  const float* scaling = (const float*)d_in[4];
  const int* ids = (const int*)d_in[5];
  float* out = (float*)d_out;
  char* ws = (char*)d_ws;

  int* cnt = (int*)(ws + CNT_OFF);
  int* perm = (int*)(ws + PERM_OFF);
  _Float16* H = (_Float16*)(ws + H_OFF);
  _Float16* At = (_Float16*)(ws + AT_OFF);
  _Float16* Bt = (_Float16*)(ws + BT_OFF);

  hipMemsetAsync(cnt, 0, NE * sizeof(int), stream);
  hipLaunchKernelGGL(prep_kernel, dim3(1088), dim3(256), 0, stream,
                     ids, A, B, cnt, perm, At, Bt);
  hipLaunchKernelGGL(lora_stage1, dim3(272), dim3(256), 0, stream,
                     x, At, scaling, cnt, perm, H);
  hipLaunchKernelGGL(lora_stage2, dim3(4288), dim3(256), 0, stream,
                     baseo, Bt, H, cnt, perm, out);
}

// Round 2
// 300.396 us; speedup vs baseline: 1.5474x; 1.5474x over previous
//
#include <hip/hip_runtime.h>

#define TT 16384
#define DD 4096
#define OO 4096
#define NE 8
#define RRK 64
#define KSPLIT 4
#define KCHUNK 1024

typedef _Float16 f16x8 __attribute__((ext_vector_type(8)));
typedef float f32x4 __attribute__((ext_vector_type(4)));

// workspace layout (bytes)
#define CNT_OFF 0            // 8 ints
#define PERM_OFF 1024        // 8*TT ints = 512KB
#define AT_OFF (1u << 20)    // 8*64*4096 f16 = 4MB: A^T [e][r][k]
#define BT_OFF (5u << 20)    // 8*4096*64 f16 = 4MB: B^T [e][o][r]
#define HP_OFF (9u << 20)    // 4*TT*64 f16 = 8MB: H k-partials [s][t][r], unscaled

// ---------------------------------------------------------------------------
// prep: scatter tokens into per-adapter buckets; transpose+cast A and B to f16
// ---------------------------------------------------------------------------
__global__ void prep_kernel(const int* __restrict__ ids,
                            const float* __restrict__ A,
                            const float* __restrict__ B,
                            int* __restrict__ cnt,
                            int* __restrict__ perm,
                            _Float16* __restrict__ At,
                            _Float16* __restrict__ Bt) {
  const int bid = blockIdx.x, tid = threadIdx.x;
  if (bid < 64) {                      // scatter
    int t = bid * 256 + tid;
    int e = ids[t];
    int pos = atomicAdd(&cnt[e], 1);
    perm[e * TT + pos] = t;
    return;
  }
  __shared__ float tile[64][65];
  if (bid < 576) {                     // A[e][k][r] -> At[e][r][k]
    int idx = bid - 64;
    int e = idx >> 6, kb = (idx & 63) << 6;
    #pragma unroll
    for (int i = 0; i < 16; ++i) {
      int lin = i * 256 + tid;
      int kr = lin >> 6, r = lin & 63;
      tile[kr][r] = A[((size_t)e * DD + kb + kr) * RRK + r];
    }
    __syncthreads();
    #pragma unroll
    for (int i = 0; i < 16; ++i) {
      int lin = i * 256 + tid;
      int r = lin >> 6, kk = lin & 63;
      At[((size_t)e * RRK + r) * DD + kb + kk] = (_Float16)tile[kk][r];
    }
  } else {                             // B[e][r][o] -> Bt[e][o][r]
    int idx = bid - 576;
    int e = idx >> 6, ob = (idx & 63) << 6;
    #pragma unroll
    for (int i = 0; i < 16; ++i) {
      int lin = i * 256 + tid;
      int r = lin >> 6, o = lin & 63;
      tile[r][o] = B[((size_t)e * RRK + r) * OO + ob + o];
    }
    __syncthreads();
    #pragma unroll
    for (int i = 0; i < 16; ++i) {
      int lin = i * 256 + tid;
      int o = lin >> 6, r2 = lin & 63;
      Bt[((size_t)e * OO + ob + o) * RRK + r2] = (_Float16)tile[r2][o];
    }
  }
}

// ---------------------------------------------------------------------------
// stage 1: HP[s][t][:] = x[t][ks..] @ A[e][ks..]   (k-split by 4, unscaled)
// tile: 64 tokens x 64 R x K=1024 per block. 4 waves.
// ---------------------------------------------------------------------------
__global__ __launch_bounds__(256, 2)
void lora_stage1(const float* __restrict__ x,
                 const _Float16* __restrict__ At,
                 const int* __restrict__ cnt,
                 const int* __restrict__ perm,
                 _Float16* __restrict__ HP) {
  __shared__ _Float16 Xs[64][72];
  __shared__ _Float16 As[64][72];
  __shared__ int toks[64];
  const int tid = threadIdx.x;
  const int lane = tid & 63, w = tid >> 6;

  int tiles = 0;
  #pragma unroll
  for (int ee = 0; ee < NE; ++ee) tiles += (cnt[ee] + 63) >> 6;

  for (int wi = blockIdx.x; wi < tiles * KSPLIT; wi += gridDim.x) {
    int tile = wi >> 2, s = wi & 3;
    int e = 0, base = 0, n_e = 0;
    {
      int acc0 = 0;
      #pragma unroll
      for (int ee = 0; ee < NE; ++ee) {
        int c = cnt[ee];
        int tl = (c + 63) >> 6;
        if (tile >= acc0 && tile < acc0 + tl) { e = ee; base = acc0; n_e = c; }
        acc0 += tl;
      }
    }
    int m0 = (tile - base) << 6;
    int kbase = s * KCHUNK;

    if (tid < 64) {
      int rloc = m0 + tid;
      toks[tid] = (rloc < n_e) ? perm[e * TT + rloc] : -1;
    }
    __syncthreads();

    const int srow = tid >> 2;
    const int seg = (tid & 3) << 4;
    int tk0 = toks[srow];
    if (tk0 < 0) tk0 = toks[0];
    const float* xp = x + (size_t)tk0 * DD + seg;
    const _Float16* ap = At + ((size_t)e * RRK + srow) * DD + seg;

    f32x4 acc[4] = {};

    for (int k0 = kbase; k0 < kbase + KCHUNK; k0 += 64) {
      float4 v0 = *(const float4*)(xp + k0);
      float4 v1 = *(const float4*)(xp + k0 + 4);
      float4 v2 = *(const float4*)(xp + k0 + 8);
      float4 v3 = *(const float4*)(xp + k0 + 12);
      f16x8 xa, xb;
      xa[0] = (_Float16)v0.x; xa[1] = (_Float16)v0.y;
      xa[2] = (_Float16)v0.z; xa[3] = (_Float16)v0.w;
      xa[4] = (_Float16)v1.x; xa[5] = (_Float16)v1.y;
      xa[6] = (_Float16)v1.z; xa[7] = (_Float16)v1.w;
      xb[0] = (_Float16)v2.x; xb[1] = (_Float16)v2.y;
      xb[2] = (_Float16)v2.z; xb[3] = (_Float16)v2.w;
      xb[4] = (_Float16)v3.x; xb[5] = (_Float16)v3.y;
      xb[6] = (_Float16)v3.z; xb[7] = (_Float16)v3.w;
      *(f16x8*)&Xs[srow][seg] = xa;
      *(f16x8*)&Xs[srow][seg + 8] = xb;
      *(f16x8*)&As[srow][seg] = *(const f16x8*)(ap + k0);
      *(f16x8*)&As[srow][seg + 8] = *(const f16x8*)(ap + k0 + 8);
      __syncthreads();

      const int mr = w * 16 + (lane & 15);
      const int kq = (lane >> 4) << 3;
      #pragma unroll
      for (int ks = 0; ks < 2; ++ks) {
        f16x8 af = *(const f16x8*)&Xs[mr][ks * 32 + kq];
        #pragma unroll
        for (int nf = 0; nf < 4; ++nf) {
          f16x8 bfr = *(const f16x8*)&As[nf * 16 + (lane & 15)][ks * 32 + kq];
          acc[nf] = __builtin_amdgcn_mfma_f32_16x16x32_f16(af, bfr, acc[nf], 0, 0, 0);
        }
      }
      __syncthreads();
    }

    // partial epilogue (unscaled, f16)
    const int rq = (lane >> 4) << 2;
    #pragma unroll
    for (int rg = 0; rg < 4; ++rg) {
      int tk = toks[w * 16 + rq + rg];
      if (tk >= 0) {
        _Float16* hp = HP + ((size_t)s * TT + tk) * RRK + (lane & 15);
        #pragma unroll
        for (int nf = 0; nf < 4; ++nf) {
          hp[nf * 16] = (_Float16)acc[nf][rg];
        }
      }
    }
    __syncthreads();
  }
}

// ---------------------------------------------------------------------------
// stage 2: out[t][:] = base[t][:] + H[t] @ B[e]
// Operands swapped: D = B^T(A-op) x H^T(B-op) -> lane holds 4 consecutive
// output cols of one token row -> float4 epilogue. Tile 64 tok x 256 cols.
// Hs staging folds the 4-way k-partial reduction + per-adapter scaling.
// ---------------------------------------------------------------------------
__global__ __launch_bounds__(256, 2)
void lora_stage2(const float* __restrict__ baseo,
                 const _Float16* __restrict__ Bt,
                 const _Float16* __restrict__ HP,
                 const float* __restrict__ scaling,
                 const int* __restrict__ cnt,
                 const int* __restrict__ perm,
                 float* __restrict__ out) {
  __shared__ _Float16 Hs[64][72];
  __shared__ _Float16 Bs[256][72];
  __shared__ int toks[64];
  const int tid = threadIdx.x;
  const int lane = tid & 63, w = tid >> 6;

  int tot = 0;
  #pragma unroll
  for (int ee = 0; ee < NE; ++ee) tot += ((cnt[ee] + 63) >> 6) << 4;

  for (int wi = blockIdx.x; wi < tot; wi += gridDim.x) {
    int e = 0, base = 0, n_e = 0;
    {
      int acc0 = 0;
      #pragma unroll
      for (int ee = 0; ee < NE; ++ee) {
        int c = cnt[ee];
        int tl = ((c + 63) >> 6) << 4;
        if (wi >= acc0 && wi < acc0 + tl) { e = ee; base = acc0; n_e = c; }
        acc0 += tl;
      }
    }
    int local = wi - base;
    int tiles_m = (n_e + 63) >> 6;
    int mt = local % tiles_m;           // consecutive blocks share the B tile
    int nt = local / tiles_m;
    int m0 = mt << 6, o0 = nt << 8;

    if (tid < 64) {
      int rloc = m0 + tid;
      toks[tid] = (rloc < n_e) ? perm[e * TT + rloc] : -1;
    }
    __syncthreads();

    // stage Bs: 256 o-rows x 64 r
    {
      const f16x8* bp = (const f16x8*)(Bt + ((size_t)e * OO + o0 + tid) * RRK);
      #pragma unroll
      for (int j = 0; j < 8; ++j) *(f16x8*)&Bs[tid][j * 8] = bp[j];
    }
    // stage Hs: 64 token rows x 64 r, reducing 4 k-partials + scaling
    {
      float s_e = scaling[e];
      int srow = tid >> 2, seg = (tid & 3) << 4;
      int tk = toks[srow];
      if (tk < 0) tk = toks[0];
      float sum[16];
      #pragma unroll
      for (int i = 0; i < 16; ++i) sum[i] = 0.f;
      #pragma unroll
      for (int s = 0; s < KSPLIT; ++s) {
        const f16x8* hp = (const f16x8*)(HP + ((size_t)s * TT + tk) * RRK + seg);
        f16x8 h0 = hp[0], h1 = hp[1];
        #pragma unroll
        for (int i = 0; i < 8; ++i) { sum[i] += (float)h0[i]; sum[8 + i] += (float)h1[i]; }
      }
      f16x8 o0v, o1v;
      #pragma unroll
      for (int i = 0; i < 8; ++i) { o0v[i] = (_Float16)(sum[i] * s_e); o1v[i] = (_Float16)(sum[8 + i] * s_e); }
      *(f16x8*)&Hs[srow][seg] = o0v;
      *(f16x8*)&Hs[srow][seg + 8] = o1v;
    }
    __syncthreads();

    f32x4 acc[16] = {};
    const int kq = (lane >> 4) << 3;
    const int lr = lane & 15;
    #pragma unroll
    for (int ks = 0; ks < 2; ++ks) {
      f16x8 hf = *(const f16x8*)&Hs[w * 16 + lr][ks * 32 + kq];   // B-operand: tokens
      #pragma unroll
      for (int of = 0; of < 16; ++of) {
        f16x8 bfr = *(const f16x8*)&Bs[of * 16 + lr][ks * 32 + kq]; // A-operand: o rows
        acc[of] = __builtin_amdgcn_mfma_f32_16x16x32_f16(bfr, hf, acc[of], 0, 0, 0);
      }
    }

    // epilogue: lane owns token = w*16 + (lane&15), 4 consecutive cols per of
    int tk = toks[w * 16 + lr];
    if (tk >= 0) {
      const int g4 = (lane >> 4) << 2;
      size_t rowoff = (size_t)tk * OO + o0 + g4;
      #pragma unroll
      for (int of = 0; of < 16; ++of) {
        size_t off = rowoff + of * 16;
        float4 b4 = *(const float4*)(baseo + off);
        float4 r4;
        r4.x = b4.x + acc[of][0];
        r4.y = b4.y + acc[of][1];
        r4.z = b4.z + acc[of][2];
        r4.w = b4.w + acc[of][3];
        *(float4*)(out + off) = r4;
      }
    }
    __syncthreads();
  }
}

extern "C" void kernel_launch(void* const* d_in, const int* in_sizes, int n_in,
                              void* d_out, int out_size, void* d_ws, size_t ws_size,
                              hipStream_t stream) {
  const float* x = (const float*)d_in[0];
  const float* baseo = (const float*)d_in[1];
  const float* A = (const float*)d_in[2];
  const float* B = (const float*)d_in[3];
  const float* scaling = (const float*)d_in[4];
  const int* ids = (const int*)d_in[5];
  float* out = (float*)d_out;
  char* ws = (char*)d_ws;

  int* cnt = (int*)(ws + CNT_OFF);
  int* perm = (int*)(ws + PERM_OFF);
  _Float16* At = (_Float16*)(ws + AT_OFF);
  _Float16* Bt = (_Float16*)(ws + BT_OFF);
  _Float16* HP = (_Float16*)(ws + HP_OFF);

  hipMemsetAsync(cnt, 0, NE * sizeof(int), stream);
  hipLaunchKernelGGL(prep_kernel, dim3(1088), dim3(256), 0, stream,
                     ids, A, B, cnt, perm, At, Bt);
  hipLaunchKernelGGL(lora_stage1, dim3(1056), dim3(256), 0, stream,
                     x, At, cnt, perm, HP);
  hipLaunchKernelGGL(lora_stage2, dim3(4208), dim3(256), 0, stream,
                     baseo, Bt, HP, scaling, cnt, perm, out);
}